// Round 1
// baseline (1947.800 us; speedup 1.0000x reference)
//
#include <hip/hip_runtime.h>
#include <math.h>

// ---------------------------------------------------------------------------
// FrFDConv: w = FrFT2D-derived 3x3 kernel from spec, then 3x3 conv (pad 1).
// Round 1 strategy: fp32 direct conv (VALU), isolate FrFT correctness.
//   - Kernel 1: spec2kernel — per-filter 3-point chirp FrFT (both axes),
//               polar combine, write wt[ci][tap][co] fp32 into d_ws.
//   - Kernel 2: conv3x3 — tile co64 x w112 per (n,h), LDS-staged x + weights,
//               register-rotating 3-tap window, 28 outputs/thread.
// ---------------------------------------------------------------------------

#define PI_F 3.14159265358979323846f

struct C2 { float re, im; };

__device__ __forceinline__ C2 cmul(C2 a, C2 b) {
    return { a.re * b.re - a.im * b.im, a.re * b.im + a.im * b.re };
}
__device__ __forceinline__ C2 cadd3(C2 a, C2 b, C2 c) {
    return { a.re + b.re + c.re, a.im + b.im + c.im };
}
__device__ __forceinline__ C2 cexpi(float ph) {
    float s, c;
    sincosf(ph, &s, &c);
    return { c, s };
}

struct FrftConsts {
    C2 c1[3], c2[3];
    float rs;   // 1/sqrt(|sin a|+1e-12) * 1/3 folded at use site
};

// 1-D FrFT of 3 complex values, exactly mirroring the reference:
//   ifftshift -> *c1 -> fft3 -> *c2 -> ifft3 -> *c1 * rs -> fftshift
// N=3: ifftshift(x)[i] = x[(i+1)%3]; fftshift(y)[i] = y[(i+2)%3];
// n = arange(-3//2, 3//2) = [-2,-1,0] -> n^2 = [4,1,0] (baked into c1/c2).
__device__ __forceinline__ void frft3(C2& a0, C2& a1, C2& a2, const FrftConsts& K) {
    // ifftshift then chirp c1
    C2 u0 = cmul(a1, K.c1[0]);
    C2 u1 = cmul(a2, K.c1[1]);
    C2 u2 = cmul(a0, K.c1[2]);
    const C2 w  = { -0.5f, -0.8660254037844386f };  // e^{-2*pi*i/3}
    const C2 wc = { -0.5f,  0.8660254037844386f };  // conj(w) = w^2
    // forward DFT3
    C2 U0 = cadd3(u0, u1, u2);
    C2 U1 = cadd3(u0, cmul(u1, w),  cmul(u2, wc));
    C2 U2 = cadd3(u0, cmul(u1, wc), cmul(u2, w));
    // * c2
    C2 V0 = cmul(U0, K.c2[0]);
    C2 V1 = cmul(U1, K.c2[1]);
    C2 V2 = cmul(U2, K.c2[2]);
    // inverse DFT3 (1/3 folded into scale)
    C2 v0 = cadd3(V0, V1, V2);
    C2 v1 = cadd3(V0, cmul(V1, wc), cmul(V2, w));
    C2 v2 = cadd3(V0, cmul(V1, w),  cmul(V2, wc));
    // * c1 * rs/3
    float s = K.rs * (1.0f / 3.0f);
    C2 y0 = cmul(v0, K.c1[0]); y0.re *= s; y0.im *= s;
    C2 y1 = cmul(v1, K.c1[1]); y1.re *= s; y1.im *= s;
    C2 y2 = cmul(v2, K.c1[2]); y2.re *= s; y2.im *= s;
    // fftshift
    a0 = y2; a1 = y0; a2 = y1;
}

// One thread per (co,ci) filter. Writes wt[(ci*9 + tap)*64 + co].
__global__ void spec2kernel(const float* __restrict__ spec,
                            const float* __restrict__ alpha_p,
                            const float* __restrict__ polar_w,
                            float* __restrict__ wt) {
    int f = blockIdx.x * blockDim.x + threadIdx.x;
    if (f >= 64 * 64) return;
    int co = f >> 6, ci = f & 63;

    float a = alpha_p[0];
    a = fminf(fmaxf(a, 1e-4f), 2.0f - 1e-4f);
    float alph  = a * (PI_F * 0.5f);
    float tana2 = tanf(a * (PI_F * 0.25f));
    float sina  = sinf(alph);

    FrftConsts K;
    const float n2[3] = { 4.0f, 1.0f, 0.0f };  // (k-2)^2 for k=0,1,2
#pragma unroll
    for (int k = 0; k < 3; ++k) {
        K.c1[k] = cexpi(-PI_F * n2[k] * tana2 * (1.0f / 3.0f));
        K.c2[k] = cexpi(-PI_F * n2[k] / (3.0f * sina));
    }
    K.rs = 1.0f / sqrtf(fabsf(sina) + 1e-12f);

    C2 z[3][3];
    const float* sp = spec + (size_t)f * 9;
#pragma unroll
    for (int r = 0; r < 3; ++r)
#pragma unroll
        for (int c = 0; c < 3; ++c)
            z[r][c] = { sp[r * 3 + c], 0.0f };

    // axis -1 first (each row), then axis -2 (each column) — matches frft2d.
#pragma unroll
    for (int r = 0; r < 3; ++r) frft3(z[r][0], z[r][1], z[r][2], K);
#pragma unroll
    for (int c = 0; c < 3; ++c) frft3(z[0][c], z[1][c], z[2][c], K);

    float pw0 = polar_w[0], pw1 = polar_w[1];
#pragma unroll
    for (int r = 0; r < 3; ++r) {
#pragma unroll
        for (int c = 0; c < 3; ++c) {
            C2 y = z[r][c];
            float mag = sqrtf(y.re * y.re + y.im * y.im);
            float ang = atan2f(y.im, y.re) * (1.0f / PI_F);
            wt[((size_t)ci * 9 + r * 3 + c) * 64 + co] = pw0 * mag + pw1 * ang;
        }
    }
}

// Direct 3x3 conv, pad 1. Block: 256 thr = co64 x 4 pixel-groups.
// Tile: one (n,h) row, 112 output pixels. Each thread: 28 contiguous pixels.
#define WTILE 112
__global__ __launch_bounds__(256) void conv3x3(const float* __restrict__ x,
                                               const float* __restrict__ wt,
                                               float* __restrict__ out) {
    __shared__ float xs[4][3][114];   // 4 ci x 3 rows x (112+2 halo)
    __shared__ float wsh[4][9][64];   // 4 ci x 9 taps x 64 co

    const int wtile = blockIdx.x;     // 0..1
    const int h     = blockIdx.y;     // 0..223
    const int n     = blockIdx.z;     // 0..15
    const int wb    = wtile * WTILE;
    const int t     = threadIdx.x;
    const int co    = t & 63;
    const int g     = t >> 6;         // pixel group 0..3 (uniform per wave)
    const int base  = g * 28;

    float acc[28];
#pragma unroll
    for (int p = 0; p < 28; ++p) acc[p] = 0.0f;

    for (int cb = 0; cb < 16; ++cb) {        // ci blocks of 4
        __syncthreads();
        // stage x: 4 ci x 3 rows x 114 px (zero-padded halo)
        for (int e = t; e < 4 * 3 * 114; e += 256) {
            int ci_l = e / 342;
            int rem  = e - ci_l * 342;
            int r    = rem / 114;
            int px   = rem - r * 114;
            int gy   = h + r - 1;
            int gx   = wb + px - 1;
            float v  = 0.0f;
            if ((unsigned)gy < 224u && (unsigned)gx < 224u)
                v = x[(((size_t)n * 64 + cb * 4 + ci_l) * 224 + gy) * 224 + gx];
            xs[ci_l][r][px] = v;
        }
        // stage weights: 4 ci x 9 taps x 64 co (coalesced)
        for (int e = t; e < 4 * 9 * 64; e += 256) {
            int ci_l = e / 576;
            int rem  = e - ci_l * 576;
            wsh[ci_l][rem / 64][rem & 63] = wt[((size_t)(cb * 4 + ci_l)) * 576 + rem];
        }
        __syncthreads();

#pragma unroll
        for (int ci_l = 0; ci_l < 4; ++ci_l) {
            float w0[3], w1[3], w2[3];
#pragma unroll
            for (int r = 0; r < 3; ++r) {
                w0[r] = wsh[ci_l][r * 3 + 0][co];
                w1[r] = wsh[ci_l][r * 3 + 1][co];
                w2[r] = wsh[ci_l][r * 3 + 2][co];
            }
#pragma unroll
            for (int r = 0; r < 3; ++r) {
                float x0 = xs[ci_l][r][base + 0];
                float x1 = xs[ci_l][r][base + 1];
#pragma unroll
                for (int p = 0; p < 28; ++p) {
                    float x2 = xs[ci_l][r][base + p + 2];
                    acc[p] += w0[r] * x0 + w1[r] * x1 + w2[r] * x2;
                    x0 = x1; x1 = x2;
                }
            }
        }
    }

    // store 28 contiguous fp32 (16B-aligned: wb+base is a multiple of 4)
    float* op = out + (((size_t)n * 64 + co) * 224 + h) * 224 + wb + base;
#pragma unroll
    for (int p = 0; p < 28; p += 4) {
        float4 v = { acc[p], acc[p + 1], acc[p + 2], acc[p + 3] };
        *reinterpret_cast<float4*>(op + p) = v;
    }
}

extern "C" void kernel_launch(void* const* d_in, const int* in_sizes, int n_in,
                              void* d_out, int out_size, void* d_ws, size_t ws_size,
                              hipStream_t stream) {
    const float* x     = (const float*)d_in[0];   // (16,64,224,224)
    const float* spec  = (const float*)d_in[1];   // (64,64,3,3)
    const float* alpha = (const float*)d_in[2];   // scalar
    const float* pw    = (const float*)d_in[3];   // (1,2,1,1)
    float* wt  = (float*)d_ws;                    // 64*64*9 fp32 = 147 KB
    float* out = (float*)d_out;                   // (16,64,224,224) fp32

    spec2kernel<<<16, 256, 0, stream>>>(spec, alpha, pw, wt);
    conv3x3<<<dim3(2, 224, 16), 256, 0, stream>>>(x, wt, out);
}

// Round 4
// 514.384 us; speedup vs baseline: 3.7867x; 3.7867x over previous
//
#include <hip/hip_runtime.h>
#include <math.h>

// ---------------------------------------------------------------------------
// FrFDConv round 4 (= round-3 source; r2/r3 benches never ran — GPU timeout):
//   k0 spec2kernel : FrFT 3x3 weights -> bf16 wt_b[co][tap][ci] (+fp32 fallback)
//   k1 transpose_x : x fp32 NCHW -> xp bf16 [n][h'][w'][ci], 226x226 padded
//   k2 border_zero : zero the pad border of xp
//   k3 conv_mfma   : tile co64 x h16 x w32, 4 waves, mfma_f32_16x16x32_bf16
// Fallback (ws too small): round-1 fp32 direct conv.
// ---------------------------------------------------------------------------

#define PI_F 3.14159265358979323846f

typedef __attribute__((ext_vector_type(8))) short  short8v;   // 8 bf16 = 4 VGPR
typedef __attribute__((ext_vector_type(4))) float  f32x4;
typedef __attribute__((ext_vector_type(8))) unsigned short ush8;

#define XP_ELEMS   (16u * 226u * 226u * 64u)          // 52,303,872
#define XP_BYTES   ((size_t)XP_ELEMS * 2)             // 104,607,744
#define WTB_BYTES  (64 * 576 * 2)                     // 73,728

__device__ __forceinline__ unsigned short f2b(float f) {
    union { float f; unsigned u; } v; v.f = f;
    unsigned u = v.u;
    return (unsigned short)((u + 0x7FFFu + ((u >> 16) & 1u)) >> 16);
}

// ---------------- FrFT weight generation ----------------
struct C2 { float re, im; };
__device__ __forceinline__ C2 cmul(C2 a, C2 b) {
    return { a.re * b.re - a.im * b.im, a.re * b.im + a.im * b.re };
}
__device__ __forceinline__ C2 cadd3(C2 a, C2 b, C2 c) {
    return { a.re + b.re + c.re, a.im + b.im + c.im };
}
__device__ __forceinline__ C2 cexpi(float ph) {
    float s, c; sincosf(ph, &s, &c); return { c, s };
}
struct FrftConsts { C2 c1[3], c2[3]; float rs; };

// 1-D FrFT of 3 complex values, exactly mirroring the reference:
//   ifftshift -> *c1 -> fft3 -> *c2 -> ifft3 -> *c1 * rs -> fftshift
// N=3: ifftshift(x)[i] = x[(i+1)%3]; fftshift(y)[i] = y[(i+2)%3];
// n = arange(-3//2, 3//2) = [-2,-1,0] -> n^2 = [4,1,0] baked into c1/c2.
__device__ __forceinline__ void frft3(C2& a0, C2& a1, C2& a2, const FrftConsts& K) {
    C2 u0 = cmul(a1, K.c1[0]);
    C2 u1 = cmul(a2, K.c1[1]);
    C2 u2 = cmul(a0, K.c1[2]);
    const C2 w  = { -0.5f, -0.8660254037844386f };
    const C2 wc = { -0.5f,  0.8660254037844386f };
    C2 U0 = cadd3(u0, u1, u2);
    C2 U1 = cadd3(u0, cmul(u1, w),  cmul(u2, wc));
    C2 U2 = cadd3(u0, cmul(u1, wc), cmul(u2, w));
    C2 V0 = cmul(U0, K.c2[0]);
    C2 V1 = cmul(U1, K.c2[1]);
    C2 V2 = cmul(U2, K.c2[2]);
    C2 v0 = cadd3(V0, V1, V2);
    C2 v1 = cadd3(V0, cmul(V1, wc), cmul(V2, w));
    C2 v2 = cadd3(V0, cmul(V1, w),  cmul(V2, wc));
    float s = K.rs * (1.0f / 3.0f);
    C2 y0 = cmul(v0, K.c1[0]); y0.re *= s; y0.im *= s;
    C2 y1 = cmul(v1, K.c1[1]); y1.re *= s; y1.im *= s;
    C2 y2 = cmul(v2, K.c1[2]); y2.re *= s; y2.im *= s;
    a0 = y2; a1 = y0; a2 = y1;
}

// One thread per (co,ci). wt_f32: [(ci*9+tap)*64+co] (fallback conv layout).
// wt_b16: [co*576 + tap*64 + ci] (MFMA A layout, tap-major K).
__global__ void spec2kernel(const float* __restrict__ spec,
                            const float* __restrict__ alpha_p,
                            const float* __restrict__ polar_w,
                            float* __restrict__ wt_f32,
                            unsigned short* __restrict__ wt_b16) {
    int f = blockIdx.x * blockDim.x + threadIdx.x;
    if (f >= 64 * 64) return;
    int co = f >> 6, ci = f & 63;

    float a = alpha_p[0];
    a = fminf(fmaxf(a, 1e-4f), 2.0f - 1e-4f);
    float alph  = a * (PI_F * 0.5f);
    float tana2 = tanf(a * (PI_F * 0.25f));
    float sina  = sinf(alph);

    FrftConsts K;
    const float n2[3] = { 4.0f, 1.0f, 0.0f };
#pragma unroll
    for (int k = 0; k < 3; ++k) {
        K.c1[k] = cexpi(-PI_F * n2[k] * tana2 * (1.0f / 3.0f));
        K.c2[k] = cexpi(-PI_F * n2[k] / (3.0f * sina));
    }
    K.rs = 1.0f / sqrtf(fabsf(sina) + 1e-12f);

    C2 z[3][3];
    const float* sp = spec + (size_t)f * 9;
#pragma unroll
    for (int r = 0; r < 3; ++r)
#pragma unroll
        for (int c = 0; c < 3; ++c)
            z[r][c] = { sp[r * 3 + c], 0.0f };

#pragma unroll
    for (int r = 0; r < 3; ++r) frft3(z[r][0], z[r][1], z[r][2], K);
#pragma unroll
    for (int c = 0; c < 3; ++c) frft3(z[0][c], z[1][c], z[2][c], K);

    float pw0 = polar_w[0], pw1 = polar_w[1];
#pragma unroll
    for (int r = 0; r < 3; ++r) {
#pragma unroll
        for (int c = 0; c < 3; ++c) {
            C2 y = z[r][c];
            float mag = sqrtf(y.re * y.re + y.im * y.im);
            float ang = atan2f(y.im, y.re) * (1.0f / PI_F);
            float wv = pw0 * mag + pw1 * ang;
            int tap = r * 3 + c;
            if (wt_f32) wt_f32[((size_t)ci * 9 + tap) * 64 + co] = wv;
            if (wt_b16) wt_b16[(size_t)co * 576 + tap * 64 + ci] = f2b(wv);
        }
    }
}

// ---------------- pre-pass: x NCHW fp32 -> xp [n][h+1][w+1][ci] bf16 ----------------
// grid (7 w-tiles of 32, 224 h, 16 n), 256 thr.
__global__ void transpose_x(const float* __restrict__ x,
                            unsigned short* __restrict__ xp) {
    __shared__ unsigned short lt[32][72];   // [w][ci], padded stride 72
    const int t  = threadIdx.x;
    const int w0 = blockIdx.x * 32;
    const int h  = blockIdx.y;
    const int n  = blockIdx.z;

    // load 512 float4 tasks: (ci, q) -> x[n][ci][h][w0+4q .. +3]
#pragma unroll
    for (int i = 0; i < 2; ++i) {
        int task = t + i * 256;
        int ci = task >> 3, q = task & 7;
        float4 v = *reinterpret_cast<const float4*>(
            x + (((size_t)n * 64 + ci) * 224 + h) * 224 + w0 + 4 * q);
        lt[4 * q + 0][ci] = f2b(v.x);
        lt[4 * q + 1][ci] = f2b(v.y);
        lt[4 * q + 2][ci] = f2b(v.z);
        lt[4 * q + 3][ci] = f2b(v.w);
    }
    __syncthreads();
    // write 256 ushort8 tasks: (w, c) -> xp[n][h+1][w0+w+1][8c..]
    int w = t >> 3, c = t & 7;
    ush8 v = *reinterpret_cast<const ush8*>(&lt[w][c * 8]);
    *reinterpret_cast<ush8*>(
        xp + ((size_t)(n * 226 + h + 1) * 226 + (w0 + w + 1)) * 64 + c * 8) = v;
}

// zero the pad border: 16n x 900 border px x 8 ci-chunks of 8
__global__ void border_zero(unsigned short* __restrict__ xp) {
    int idx = blockIdx.x * 256 + threadIdx.x;   // 115200 total
    if (idx >= 16 * 900 * 8) return;
    int c = idx & 7;
    int r = idx >> 3;
    int p = r % 900;
    int n = r / 900;
    int hh, ww;
    if (p < 226)      { hh = 0;   ww = p; }
    else if (p < 452) { hh = 225; ww = p - 226; }
    else {
        int p2 = p - 452;                 // 0..447
        hh = 1 + (p2 >> 1);               // 1..224
        ww = (p2 & 1) ? 225 : 0;
    }
    ush8 z = {0, 0, 0, 0, 0, 0, 0, 0};
    *reinterpret_cast<ush8*>(
        xp + ((size_t)(n * 226 + hh) * 226 + ww) * 64 + c * 8) = z;
}

// ---------------- main conv: implicit GEMM, mfma_f32_16x16x32_bf16 ----------------
// Block tile co64 x h16 x w32. 4 waves, wave = 4 h-rows x 32 w x 64 co.
// K = (ci-half, tap, ci32): each K=32 step = one tap x 32 ci (shifted read).
#define XS_BYTES 39168          // 612 s-slots * 64B (swizzled)
#define WA_STRIDE 272           // phase A: 4 taps*64 + 16 pad (odd chunk count)
#define WB_STRIDE 336           // phase B: 5 taps*64 + 16 pad
#define WL_BYTES  21504         // 64 * 336

__global__ __launch_bounds__(256, 2) void conv_mfma(
        const unsigned short* __restrict__ xp,
        const unsigned short* __restrict__ wtb,
        float* __restrict__ out) {
    __shared__ __attribute__((aligned(128))) char lds[XS_BYTES + WL_BYTES];
    char* xs = lds;
    char* wl = lds + XS_BYTES;

    const int t    = threadIdx.x;
    const int lane = t & 63;
    const int wv   = t >> 6;
    const int li   = lane & 15;
    const int ch   = lane >> 4;
    const int wb   = blockIdx.x * 32;
    const int hb   = blockIdx.y * 16;
    const int n    = blockIdx.z;

    f32x4 acc[4][8];
#pragma unroll
    for (int i = 0; i < 4; ++i)
#pragma unroll
        for (int j = 0; j < 8; ++j) acc[i][j] = (f32x4){0.f, 0.f, 0.f, 0.f};

    const int sbase = 4 * wv * 34 + li;   // per-lane s base (row 0, tap offset 0)

    for (int half = 0; half < 2; ++half) {
        __syncthreads();
        // ---- stage x half: 18 rows x 34 w-slots x 32 ci (swizzled) ----
        for (int task = t; task < 2448; task += 256) {
            int c = task & 3, s = task >> 2;
            int row = s / 34, wsl = s - row * 34;
            ush8 v = *reinterpret_cast<const ush8*>(
                xp + ((size_t)(n * 226 + hb + row) * 226 + wb + wsl) * 64
                   + half * 32 + c * 8);
            int b = (s << 6) + (c << 4);
            b ^= ((s >> 1) & 3) << 4;
            *reinterpret_cast<ush8*>(xs + b) = v;
        }
        // ---- stage weights phase A: taps 0..3 ----
        for (int task = t; task < 1024; task += 256) {
            int c = task & 3, r = task >> 2;       // r = co*4 + tapl
            int co = r >> 2, tapl = r & 3;
            ush8 v = *reinterpret_cast<const ush8*>(
                wtb + (size_t)co * 576 + tapl * 64 + half * 32 + c * 8);
            *reinterpret_cast<ush8*>(wl + co * WA_STRIDE + tapl * 64 + (c << 4)) = v;
        }
        __syncthreads();

        // ---- K-steps: taps 0..3 ----
#pragma unroll
        for (int tap = 0; tap < 4; ++tap) {
            const int r_off = tap / 3, c_off = tap % 3;
            short8v af[4], bf[8];
#pragma unroll
            for (int cs = 0; cs < 4; ++cs) {
                int b = (cs * 16 + li) * WA_STRIDE + tap * 64 + (ch << 4);
                af[cs] = *reinterpret_cast<const short8v*>(wl + b);
            }
#pragma unroll
            for (int p = 0; p < 8; ++p) {
                int s = sbase + ((p >> 1) + r_off) * 34 + (p & 1) * 16 + c_off;
                int b = (s << 6) + (ch << 4);
                b ^= ((s >> 1) & 3) << 4;
                bf[p] = *reinterpret_cast<const short8v*>(xs + b);
            }
#pragma unroll
            for (int cs = 0; cs < 4; ++cs)
#pragma unroll
                for (int p = 0; p < 8; ++p)
                    acc[cs][p] = __builtin_amdgcn_mfma_f32_16x16x32_bf16(
                        af[cs], bf[p], acc[cs][p], 0, 0, 0);
        }

        __syncthreads();
        // ---- stage weights phase B: taps 4..8 ----
        for (int task = t; task < 1280; task += 256) {
            int c = task & 3, r = task >> 2;       // r = co*5 + tapl
            int co = r / 5, tapl = r - co * 5;
            ush8 v = *reinterpret_cast<const ush8*>(
                wtb + (size_t)co * 576 + (4 + tapl) * 64 + half * 32 + c * 8);
            *reinterpret_cast<ush8*>(wl + co * WB_STRIDE + tapl * 64 + (c << 4)) = v;
        }
        __syncthreads();

        // ---- K-steps: taps 4..8 ----
#pragma unroll
        for (int tap = 4; tap < 9; ++tap) {
            const int r_off = tap / 3, c_off = tap % 3;
            short8v af[4], bf[8];
#pragma unroll
            for (int cs = 0; cs < 4; ++cs) {
                int b = (cs * 16 + li) * WB_STRIDE + (tap - 4) * 64 + (ch << 4);
                af[cs] = *reinterpret_cast<const short8v*>(wl + b);
            }
#pragma unroll
            for (int p = 0; p < 8; ++p) {
                int s = sbase + ((p >> 1) + r_off) * 34 + (p & 1) * 16 + c_off;
                int b = (s << 6) + (ch << 4);
                b ^= ((s >> 1) & 3) << 4;
                bf[p] = *reinterpret_cast<const short8v*>(xs + b);
            }
#pragma unroll
            for (int cs = 0; cs < 4; ++cs)
#pragma unroll
                for (int p = 0; p < 8; ++p)
                    acc[cs][p] = __builtin_amdgcn_mfma_f32_16x16x32_bf16(
                        af[cs], bf[p], acc[cs][p], 0, 0, 0);
        }
    }

    // ---- epilogue: D[row=4ch+j][col=li] -> out[n][co][h][w] ----
#pragma unroll
    for (int cs = 0; cs < 4; ++cs) {
#pragma unroll
        for (int p = 0; p < 8; ++p) {
            int h = hb + wv * 4 + (p >> 1);
            int w = wb + (p & 1) * 16 + li;
#pragma unroll
            for (int j = 0; j < 4; ++j) {
                int co = cs * 16 + ch * 4 + j;
                out[((size_t)(n * 64 + co) * 224 + h) * 224 + w] = acc[cs][p][j];
            }
        }
    }
}

// ---------------- fallback: round-1 fp32 direct conv ----------------
#define WTILE 112
__global__ __launch_bounds__(256) void conv3x3(const float* __restrict__ x,
                                               const float* __restrict__ wt,
                                               float* __restrict__ out) {
    __shared__ float xsm[4][3][114];
    __shared__ float wsh[4][9][64];

    const int wtile = blockIdx.x;
    const int h     = blockIdx.y;
    const int n     = blockIdx.z;
    const int wb    = wtile * WTILE;
    const int t     = threadIdx.x;
    const int co    = t & 63;
    const int g     = t >> 6;
    const int base  = g * 28;

    float acc[28];
#pragma unroll
    for (int p = 0; p < 28; ++p) acc[p] = 0.0f;

    for (int cb = 0; cb < 16; ++cb) {
        __syncthreads();
        for (int e = t; e < 4 * 3 * 114; e += 256) {
            int ci_l = e / 342;
            int rem  = e - ci_l * 342;
            int r    = rem / 114;
            int px   = rem - r * 114;
            int gy   = h + r - 1;
            int gx   = wb + px - 1;
            float v  = 0.0f;
            if ((unsigned)gy < 224u && (unsigned)gx < 224u)
                v = x[(((size_t)n * 64 + cb * 4 + ci_l) * 224 + gy) * 224 + gx];
            xsm[ci_l][r][px] = v;
        }
        for (int e = t; e < 4 * 9 * 64; e += 256) {
            int ci_l = e / 576;
            int rem  = e - ci_l * 576;
            wsh[ci_l][rem / 64][rem & 63] = wt[((size_t)(cb * 4 + ci_l)) * 576 + rem];
        }
        __syncthreads();

#pragma unroll
        for (int ci_l = 0; ci_l < 4; ++ci_l) {
            float w0[3], w1[3], w2[3];
#pragma unroll
            for (int r = 0; r < 3; ++r) {
                w0[r] = wsh[ci_l][r * 3 + 0][co];
                w1[r] = wsh[ci_l][r * 3 + 1][co];
                w2[r] = wsh[ci_l][r * 3 + 2][co];
            }
#pragma unroll
            for (int r = 0; r < 3; ++r) {
                float x0 = xsm[ci_l][r][base + 0];
                float x1 = xsm[ci_l][r][base + 1];
#pragma unroll
                for (int p = 0; p < 28; ++p) {
                    float x2 = xsm[ci_l][r][base + p + 2];
                    acc[p] += w0[r] * x0 + w1[r] * x1 + w2[r] * x2;
                    x0 = x1; x1 = x2;
                }
            }
        }
    }

    float* op = out + (((size_t)n * 64 + co) * 224 + h) * 224 + wb + base;
#pragma unroll
    for (int p = 0; p < 28; p += 4) {
        float4 v = { acc[p], acc[p + 1], acc[p + 2], acc[p + 3] };
        *reinterpret_cast<float4*>(op + p) = v;
    }
}

extern "C" void kernel_launch(void* const* d_in, const int* in_sizes, int n_in,
                              void* d_out, int out_size, void* d_ws, size_t ws_size,
                              hipStream_t stream) {
    const float* x     = (const float*)d_in[0];   // (16,64,224,224)
    const float* spec  = (const float*)d_in[1];   // (64,64,3,3)
    const float* alpha = (const float*)d_in[2];
    const float* pw    = (const float*)d_in[3];
    float* out = (float*)d_out;

    if (ws_size >= XP_BYTES + WTB_BYTES) {
        unsigned short* xp  = (unsigned short*)d_ws;
        unsigned short* wtb = (unsigned short*)((char*)d_ws + XP_BYTES);

        spec2kernel<<<16, 256, 0, stream>>>(spec, alpha, pw, nullptr, wtb);
        transpose_x<<<dim3(7, 224, 16), 256, 0, stream>>>(x, xp);
        border_zero<<<450, 256, 0, stream>>>(xp);
        conv_mfma<<<dim3(7, 14, 16), 256, 0, stream>>>(xp, wtb, out);
    } else {
        float* wt = (float*)d_ws;                 // fp32 fallback layout
        spec2kernel<<<16, 256, 0, stream>>>(spec, alpha, pw, wt, nullptr);
        conv3x3<<<dim3(2, 224, 16), 256, 0, stream>>>(x, wt, out);
    }
}

// Round 6
// 438.425 us; speedup vs baseline: 4.4427x; 1.1733x over previous
//
#include <hip/hip_runtime.h>
#include <math.h>

// ---------------------------------------------------------------------------
// FrFDConv round 6 (= round-5 source; r5 bench never ran — GPU timeout):
//   k0 spec2kernel : FrFT 3x3 weights -> bf16 wt_b[co][kk=(half,tap)][ci32]
//   k1 transpose_x : x fp32 NCHW -> xp bf16 [n][h'][w'][ci], 226x226 padded
//                    (4 h-rows per block)
//   k2 border_zero : zero the pad border of xp
//   k3 conv_mfma   : tile co64 x h16 x w32, 4 waves, ALL weights (74.75KB,
//                    bank-padded stride 1168) + both x halves (78.3KB) in LDS,
//                    single __syncthreads, 576 MFMA/wave.
// Fallback (ws too small): round-1 fp32 direct conv.
// ---------------------------------------------------------------------------

#define PI_F 3.14159265358979323846f

typedef __attribute__((ext_vector_type(8))) short  short8v;   // 8 bf16 = 4 VGPR
typedef __attribute__((ext_vector_type(4))) float  f32x4;
typedef __attribute__((ext_vector_type(8))) unsigned short ush8;

#define XP_ELEMS   (16u * 226u * 226u * 64u)          // 52,303,872
#define XP_BYTES   ((size_t)XP_ELEMS * 2)             // 104,607,744
#define WTB_BYTES  (64 * 576 * 2)                     // 73,728

__device__ __forceinline__ unsigned short f2b(float f) {
    union { float f; unsigned u; } v; v.f = f;
    unsigned u = v.u;
    return (unsigned short)((u + 0x7FFFu + ((u >> 16) & 1u)) >> 16);
}

// ---------------- FrFT weight generation ----------------
struct C2 { float re, im; };
__device__ __forceinline__ C2 cmul(C2 a, C2 b) {
    return { a.re * b.re - a.im * b.im, a.re * b.im + a.im * b.re };
}
__device__ __forceinline__ C2 cadd3(C2 a, C2 b, C2 c) {
    return { a.re + b.re + c.re, a.im + b.im + c.im };
}
__device__ __forceinline__ C2 cexpi(float ph) {
    float s, c; sincosf(ph, &s, &c); return { c, s };
}
struct FrftConsts { C2 c1[3], c2[3]; float rs; };

// 1-D FrFT of 3 complex values, exactly mirroring the reference:
//   ifftshift -> *c1 -> fft3 -> *c2 -> ifft3 -> *c1 * rs -> fftshift
// N=3: ifftshift(x)[i] = x[(i+1)%3]; fftshift(y)[i] = y[(i+2)%3];
// n = arange(-3//2, 3//2) = [-2,-1,0] -> n^2 = [4,1,0] baked into c1/c2.
__device__ __forceinline__ void frft3(C2& a0, C2& a1, C2& a2, const FrftConsts& K) {
    C2 u0 = cmul(a1, K.c1[0]);
    C2 u1 = cmul(a2, K.c1[1]);
    C2 u2 = cmul(a0, K.c1[2]);
    const C2 w  = { -0.5f, -0.8660254037844386f };
    const C2 wc = { -0.5f,  0.8660254037844386f };
    C2 U0 = cadd3(u0, u1, u2);
    C2 U1 = cadd3(u0, cmul(u1, w),  cmul(u2, wc));
    C2 U2 = cadd3(u0, cmul(u1, wc), cmul(u2, w));
    C2 V0 = cmul(U0, K.c2[0]);
    C2 V1 = cmul(U1, K.c2[1]);
    C2 V2 = cmul(U2, K.c2[2]);
    C2 v0 = cadd3(V0, V1, V2);
    C2 v1 = cadd3(V0, cmul(V1, wc), cmul(V2, w));
    C2 v2 = cadd3(V0, cmul(V1, w),  cmul(V2, wc));
    float s = K.rs * (1.0f / 3.0f);
    C2 y0 = cmul(v0, K.c1[0]); y0.re *= s; y0.im *= s;
    C2 y1 = cmul(v1, K.c1[1]); y1.re *= s; y1.im *= s;
    C2 y2 = cmul(v2, K.c1[2]); y2.re *= s; y2.im *= s;
    a0 = y2; a1 = y0; a2 = y1;
}

// One thread per (co,ci). wt_f32: [(ci*9+tap)*64+co] (fallback conv layout).
// wt_b16: [co*576 + (ci/32)*288 + tap*32 + (ci&31)]  (K-order: half, tap, ci32)
__global__ void spec2kernel(const float* __restrict__ spec,
                            const float* __restrict__ alpha_p,
                            const float* __restrict__ polar_w,
                            float* __restrict__ wt_f32,
                            unsigned short* __restrict__ wt_b16) {
    int f = blockIdx.x * blockDim.x + threadIdx.x;
    if (f >= 64 * 64) return;
    int co = f >> 6, ci = f & 63;

    float a = alpha_p[0];
    a = fminf(fmaxf(a, 1e-4f), 2.0f - 1e-4f);
    float alph  = a * (PI_F * 0.5f);
    float tana2 = tanf(a * (PI_F * 0.25f));
    float sina  = sinf(alph);

    FrftConsts K;
    const float n2[3] = { 4.0f, 1.0f, 0.0f };
#pragma unroll
    for (int k = 0; k < 3; ++k) {
        K.c1[k] = cexpi(-PI_F * n2[k] * tana2 * (1.0f / 3.0f));
        K.c2[k] = cexpi(-PI_F * n2[k] / (3.0f * sina));
    }
    K.rs = 1.0f / sqrtf(fabsf(sina) + 1e-12f);

    C2 z[3][3];
    const float* sp = spec + (size_t)f * 9;
#pragma unroll
    for (int r = 0; r < 3; ++r)
#pragma unroll
        for (int c = 0; c < 3; ++c)
            z[r][c] = { sp[r * 3 + c], 0.0f };

#pragma unroll
    for (int r = 0; r < 3; ++r) frft3(z[r][0], z[r][1], z[r][2], K);
#pragma unroll
    for (int c = 0; c < 3; ++c) frft3(z[0][c], z[1][c], z[2][c], K);

    float pw0 = polar_w[0], pw1 = polar_w[1];
#pragma unroll
    for (int r = 0; r < 3; ++r) {
#pragma unroll
        for (int c = 0; c < 3; ++c) {
            C2 y = z[r][c];
            float mag = sqrtf(y.re * y.re + y.im * y.im);
            float ang = atan2f(y.im, y.re) * (1.0f / PI_F);
            float wv = pw0 * mag + pw1 * ang;
            int tap = r * 3 + c;
            if (wt_f32) wt_f32[((size_t)ci * 9 + tap) * 64 + co] = wv;
            if (wt_b16) wt_b16[(size_t)co * 576 + (ci >> 5) * 288 + tap * 32
                               + (ci & 31)] = f2b(wv);
        }
    }
}

// ---------------- pre-pass: x NCHW fp32 -> xp [n][h+1][w+1][ci] bf16 ----------------
// grid (7 w-tiles of 32, 56 h-quads, 16 n), 256 thr; 4 h-rows per block.
__global__ void transpose_x(const float* __restrict__ x,
                            unsigned short* __restrict__ xp) {
    __shared__ unsigned short lt[32][72];   // [w][ci], padded stride 72
    const int t  = threadIdx.x;
    const int w0 = blockIdx.x * 32;
    const int n  = blockIdx.z;

    for (int it = 0; it < 4; ++it) {
        const int h = blockIdx.y * 4 + it;
        if (it) __syncthreads();
        // load 512 float4 tasks: (ci, q) -> x[n][ci][h][w0+4q .. +3]
#pragma unroll
        for (int i = 0; i < 2; ++i) {
            int task = t + i * 256;
            int ci = task >> 3, q = task & 7;
            float4 v = *reinterpret_cast<const float4*>(
                x + (((size_t)n * 64 + ci) * 224 + h) * 224 + w0 + 4 * q);
            lt[4 * q + 0][ci] = f2b(v.x);
            lt[4 * q + 1][ci] = f2b(v.y);
            lt[4 * q + 2][ci] = f2b(v.z);
            lt[4 * q + 3][ci] = f2b(v.w);
        }
        __syncthreads();
        // write 256 ushort8 tasks: (w, c) -> xp[n][h+1][w0+w+1][8c..]
        int w = t >> 3, c = t & 7;
        ush8 v = *reinterpret_cast<const ush8*>(&lt[w][c * 8]);
        *reinterpret_cast<ush8*>(
            xp + ((size_t)(n * 226 + h + 1) * 226 + (w0 + w + 1)) * 64 + c * 8) = v;
    }
}

// zero the pad border: 16n x 900 border px x 8 ci-chunks of 8
__global__ void border_zero(unsigned short* __restrict__ xp) {
    int idx = blockIdx.x * 256 + threadIdx.x;   // 115200 total
    if (idx >= 16 * 900 * 8) return;
    int c = idx & 7;
    int r = idx >> 3;
    int p = r % 900;
    int n = r / 900;
    int hh, ww;
    if (p < 226)      { hh = 0;   ww = p; }
    else if (p < 452) { hh = 225; ww = p - 226; }
    else {
        int p2 = p - 452;                 // 0..447
        hh = 1 + (p2 >> 1);               // 1..224
        ww = (p2 & 1) ? 225 : 0;
    }
    ush8 z = {0, 0, 0, 0, 0, 0, 0, 0};
    *reinterpret_cast<ush8*>(
        xp + ((size_t)(n * 226 + hh) * 226 + ww) * 64 + c * 8) = z;
}

// ---------------- main conv: implicit GEMM, mfma_f32_16x16x32_bf16 ----------------
// Block tile co64 x h16 x w32. 4 waves, wave = 4 h-rows x 32 w x 64 co.
// Full K=576 resident: weights [64co][18kk][4ch16B] stride 1168 (74.75 KB,
// 292 dwords/co -> bank+4/co -> 2-way free), x both halves (2x39168 B,
// XOR-swizzled chunks). ONE barrier, then 18 K-steps x 32 MFMA per wave.
#define WCO_STRIDE  1168
#define WLDS_BYTES  (64 * WCO_STRIDE)       // 74752
#define XHALF_BYTES 39168                   // 612 s-slots * 64B
#define LDS_TOTAL   (WLDS_BYTES + 2 * XHALF_BYTES)   // 153088 <= 160 KiB

__global__ __launch_bounds__(256, 1) void conv_mfma(
        const unsigned short* __restrict__ xp,
        const unsigned short* __restrict__ wtb,
        float* __restrict__ out) {
    __shared__ __attribute__((aligned(128))) char lds[LDS_TOTAL];
    char* wl = lds;                    // weights
    char* xs = lds + WLDS_BYTES;       // x, two ci-halves

    const int t    = threadIdx.x;
    const int lane = t & 63;
    const int li   = lane & 15;
    const int ch   = lane >> 4;
    const int wv   = t >> 6;
    const int wb   = blockIdx.x * 32;
    const int hb   = blockIdx.y * 16;
    const int n    = blockIdx.z;

    // ---- stage weights: 4608 16B-chunks = 18/thread (from L2) ----
#pragma unroll
    for (int i = 0; i < 18; ++i) {
        int c2 = t + i * 256;
        int co = c2 / 72, r = c2 - co * 72;
        int kk = r >> 2, c4 = r & 3;
        ush8 v = *reinterpret_cast<const ush8*>(
            wtb + (size_t)co * 576 + kk * 32 + c4 * 8);
        *reinterpret_cast<ush8*>(wl + co * WCO_STRIDE + kk * 64 + (c4 << 4)) = v;
    }
    // ---- stage x: both halves, 4896 16B-chunks, swizzled dest ----
#pragma unroll
    for (int i = 0; i < 20; ++i) {
        int task = t + i * 256;
        if (task < 4896) {
            int half = task >= 2448 ? 1 : 0;
            int r    = task - half * 2448;
            int s    = r >> 2, c = r & 3;
            int row  = s / 34, wsl = s - row * 34;
            ush8 v = *reinterpret_cast<const ush8*>(
                xp + ((size_t)(n * 226 + hb + row) * 226 + wb + wsl) * 64
                   + half * 32 + c * 8);
            int b = (s << 6) + ((c ^ ((s >> 1) & 3)) << 4);
            *reinterpret_cast<ush8*>(xs + half * XHALF_BYTES + b) = v;
        }
    }
    __syncthreads();   // the ONLY barrier

    f32x4 acc[4][8];
#pragma unroll
    for (int i = 0; i < 4; ++i)
#pragma unroll
        for (int j = 0; j < 8; ++j) acc[i][j] = (f32x4){0.f, 0.f, 0.f, 0.f};

    const int sbase = 4 * wv * 34 + li;

#pragma unroll
    for (int kk = 0; kk < 18; ++kk) {
        const int half  = kk / 9;
        const int tap   = kk - half * 9;
        const int r_off = tap / 3, c_off = tap % 3;
        short8v af[4], bf[8];
#pragma unroll
        for (int cs = 0; cs < 4; ++cs) {
            af[cs] = *reinterpret_cast<const short8v*>(
                wl + (cs * 16 + li) * WCO_STRIDE + kk * 64 + (ch << 4));
        }
#pragma unroll
        for (int p = 0; p < 8; ++p) {
            int s = sbase + ((p >> 1) + r_off) * 34 + (p & 1) * 16 + c_off;
            int b = (s << 6) + ((ch ^ ((s >> 1) & 3)) << 4);
            bf[p] = *reinterpret_cast<const short8v*>(xs + half * XHALF_BYTES + b);
        }
#pragma unroll
        for (int cs = 0; cs < 4; ++cs)
#pragma unroll
            for (int p = 0; p < 8; ++p)
                acc[cs][p] = __builtin_amdgcn_mfma_f32_16x16x32_bf16(
                    af[cs], bf[p], acc[cs][p], 0, 0, 0);
    }

    // ---- epilogue: D[row=4ch+j][col=li] -> out[n][co][h][w] ----
#pragma unroll
    for (int cs = 0; cs < 4; ++cs) {
#pragma unroll
        for (int p = 0; p < 8; ++p) {
            int h = hb + wv * 4 + (p >> 1);
            int w = wb + (p & 1) * 16 + li;
#pragma unroll
            for (int j = 0; j < 4; ++j) {
                int co = cs * 16 + ch * 4 + j;
                out[((size_t)(n * 64 + co) * 224 + h) * 224 + w] = acc[cs][p][j];
            }
        }
    }
}

// ---------------- fallback: round-1 fp32 direct conv ----------------
#define WTILE 112
__global__ __launch_bounds__(256) void conv3x3(const float* __restrict__ x,
                                               const float* __restrict__ wt,
                                               float* __restrict__ out) {
    __shared__ float xsm[4][3][114];
    __shared__ float wsh[4][9][64];

    const int wtile = blockIdx.x;
    const int h     = blockIdx.y;
    const int n     = blockIdx.z;
    const int wb    = wtile * WTILE;
    const int t     = threadIdx.x;
    const int co    = t & 63;
    const int g     = t >> 6;
    const int base  = g * 28;

    float acc[28];
#pragma unroll
    for (int p = 0; p < 28; ++p) acc[p] = 0.0f;

    for (int cb = 0; cb < 16; ++cb) {
        __syncthreads();
        for (int e = t; e < 4 * 3 * 114; e += 256) {
            int ci_l = e / 342;
            int rem  = e - ci_l * 342;
            int r    = rem / 114;
            int px   = rem - r * 114;
            int gy   = h + r - 1;
            int gx   = wb + px - 1;
            float v  = 0.0f;
            if ((unsigned)gy < 224u && (unsigned)gx < 224u)
                v = x[(((size_t)n * 64 + cb * 4 + ci_l) * 224 + gy) * 224 + gx];
            xsm[ci_l][r][px] = v;
        }
        for (int e = t; e < 4 * 9 * 64; e += 256) {
            int ci_l = e / 576;
            int rem  = e - ci_l * 576;
            wsh[ci_l][rem / 64][rem & 63] = wt[((size_t)(cb * 4 + ci_l)) * 576 + rem];
        }
        __syncthreads();

#pragma unroll
        for (int ci_l = 0; ci_l < 4; ++ci_l) {
            float w0[3], w1[3], w2[3];
#pragma unroll
            for (int r = 0; r < 3; ++r) {
                w0[r] = wsh[ci_l][r * 3 + 0][co];
                w1[r] = wsh[ci_l][r * 3 + 1][co];
                w2[r] = wsh[ci_l][r * 3 + 2][co];
            }
#pragma unroll
            for (int r = 0; r < 3; ++r) {
                float x0 = xsm[ci_l][r][base + 0];
                float x1 = xsm[ci_l][r][base + 1];
#pragma unroll
                for (int p = 0; p < 28; ++p) {
                    float x2 = xsm[ci_l][r][base + p + 2];
                    acc[p] += w0[r] * x0 + w1[r] * x1 + w2[r] * x2;
                    x0 = x1; x1 = x2;
                }
            }
        }
    }

    float* op = out + (((size_t)n * 64 + co) * 224 + h) * 224 + wb + base;
#pragma unroll
    for (int p = 0; p < 28; p += 4) {
        float4 v = { acc[p], acc[p + 1], acc[p + 2], acc[p + 3] };
        *reinterpret_cast<float4*>(op + p) = v;
    }
}

extern "C" void kernel_launch(void* const* d_in, const int* in_sizes, int n_in,
                              void* d_out, int out_size, void* d_ws, size_t ws_size,
                              hipStream_t stream) {
    const float* x     = (const float*)d_in[0];   // (16,64,224,224)
    const float* spec  = (const float*)d_in[1];   // (64,64,3,3)
    const float* alpha = (const float*)d_in[2];
    const float* pw    = (const float*)d_in[3];
    float* out = (float*)d_out;

    if (ws_size >= XP_BYTES + WTB_BYTES) {
        unsigned short* xp  = (unsigned short*)d_ws;
        unsigned short* wtb = (unsigned short*)((char*)d_ws + XP_BYTES);

        spec2kernel<<<64, 64, 0, stream>>>(spec, alpha, pw, nullptr, wtb);
        transpose_x<<<dim3(7, 56, 16), 256, 0, stream>>>(x, xp);
        border_zero<<<450, 256, 0, stream>>>(xp);
        conv_mfma<<<dim3(7, 14, 16), 256, 0, stream>>>(xp, wtb, out);
    } else {
        float* wt = (float*)d_ws;                 // fp32 fallback layout
        spec2kernel<<<64, 64, 0, stream>>>(spec, alpha, pw, wt, nullptr);
        conv3x3<<<dim3(2, 224, 16), 256, 0, stream>>>(x, wt, out);
    }
}